// Round 3
// baseline (1198.338 us; speedup 1.0000x reference)
//
#include <hip/hip_runtime.h>

#define KS     11
#define HWDIM  512
#define IMG    (HWDIM*HWDIM)
#define TH     32
#define STRIPS 16              // 512 / TH
#define PLANES 96              // 32 images * 3 channels
#define GUARD  8
#define ROWW   528             // GUARD + 512 + 8
#define NPARTIAL (PLANES*STRIPS)

// XOR bank swizzle for the field-interleaved float4 row (T2 pattern):
// keeps every 16-lane phase of stride-2 col access <=2-way per bank group.
__device__ __forceinline__ int swz(int ci) { return ci ^ ((ci >> 3) & 7); }

__device__ __forceinline__ void loaduv(const float* __restrict__ pP,
                                       const float* __restrict__ tP,
                                       int r, int c0,
                                       float& u0, float& v0, float& u1, float& v1)
{
    if ((unsigned)r < HWDIM) {   // uniform branch (r is block-uniform)
        const float2 p2 = *(const float2*)(pP + (size_t)r * HWDIM + c0);
        const float2 t2 = *(const float2*)(tP + (size_t)r * HWDIM + c0);
        u0 = 0.5f*(p2.x + t2.x) + 1.0f;   // p' + t'
        v0 = 0.5f*(p2.x - t2.x);          // p' - t'
        u1 = 0.5f*(p2.y + t2.y) + 1.0f;
        v1 = 0.5f*(p2.y - t2.y);
    } else {                              // zero-pad the MAPPED values
        u0 = 0.f; v0 = 0.f; u1 = 0.f; v1 = 0.f;
    }
}

__device__ __forceinline__ float ssim_px(float mu_u, float mu_v, float Su, float Sv)
{
    const float C1v = 1e-4f, C2v = 9e-4f, EPSV = 1e-8f;
    const float uu = mu_u*mu_u, vv = mu_v*mu_v;
    const float mu2d = 0.5f*(uu - vv);   // 2 mux muy
    const float mu2s = 0.5f*(uu + vv);   // mux^2 + muy^2
    const float Sd   = 0.5f*(Su - Sv);   // 2 conv(p t)
    const float Ss   = 0.5f*(Su + Sv);   // conv(p^2)+conv(t^2)
    const float A  = mu2d + C1v;
    const float B  = Sd - mu2d + C2v;
    const float Cc = mu2s + C1v;
    const float D  = Ss - mu2s + C2v;
    return A*B / (Cc*D + EPSV);
}

// One output row: insert prefetched input row y+5 into the register ring,
// prefetch y+6, vertical conv (static ring indices via template phase PH),
// exchange through LDS, horizontal conv, SSIM.
template<int PH>
__device__ __forceinline__ float row_step(
    int y, int buf, int c0,
    const float* __restrict__ pP, const float* __restrict__ tP,
    const float (&w)[KS],
    float (&ru0)[11], float (&rv0)[11], float (&ru1)[11], float (&rv1)[11],
    float& nu0, float& nv0, float& nu1, float& nv1,
    float4 (&hbuf)[2][ROWW])
{
    constexpr int LR = (PH + 10) % 11;
    ru0[LR] = nu0; rv0[LR] = nv0; ru1[LR] = nu1; rv1[LR] = nv1;
    // prefetch next input row; consumed next step (hides HBM latency)
    loaduv(pP, tP, y + 6, c0, nu0, nv0, nu1, nv1);

    // vertical 11-tap conv of u, v, u^2, v^2 (squares recomputed from ring)
    float mu0 = 0.f, mv0 = 0.f, Su0 = 0.f, Sv0 = 0.f;
    float mu1 = 0.f, mv1 = 0.f, Su1 = 0.f, Sv1 = 0.f;
    #pragma unroll
    for (int k = 0; k < KS; ++k) {
        const int s = (PH + k) % 11;           // compile-time after unroll
        const float wk = w[k];
        float a, t;
        a = ru0[s]; t = wk*a; mu0 += t; Su0 = fmaf(t, a, Su0);
        a = rv0[s]; t = wk*a; mv0 += t; Sv0 = fmaf(t, a, Sv0);
        a = ru1[s]; t = wk*a; mu1 += t; Su1 = fmaf(t, a, Su1);
        a = rv1[s]; t = wk*a; mv1 += t; Sv1 = fmaf(t, a, Sv1);
    }

    hbuf[buf][swz(GUARD + c0)]     = make_float4(mu0, mv0, Su0, Sv0);
    hbuf[buf][swz(GUARD + c0 + 1)] = make_float4(mu1, mv1, Su1, Sv1);
    __syncthreads();

    // horizontal 11-tap conv for cols c0, c0+1 from a shared 12-tap window
    float4 A0 = make_float4(0,0,0,0), A1 = make_float4(0,0,0,0);
    #pragma unroll
    for (int k = 0; k < 12; ++k) {
        const float4 tap = hbuf[buf][swz(c0 + 3 + k)];  // ci = GUARD + c0-5+k
        if (k < 11) {
            const float wk = w[k];
            A0.x = fmaf(wk, tap.x, A0.x);
            A0.y = fmaf(wk, tap.y, A0.y);
            A0.z = fmaf(wk, tap.z, A0.z);
            A0.w = fmaf(wk, tap.w, A0.w);
        }
        if (k > 0) {
            const float wk = w[k-1];
            A1.x = fmaf(wk, tap.x, A1.x);
            A1.y = fmaf(wk, tap.y, A1.y);
            A1.z = fmaf(wk, tap.z, A1.z);
            A1.w = fmaf(wk, tap.w, A1.w);
        }
    }
    return ssim_px(A0.x, A0.y, A0.z, A0.w) + ssim_px(A1.x, A1.y, A1.z, A1.w);
}

__global__ __launch_bounds__(256, 4) void ssim_stream_kernel(
    const float* __restrict__ pred,
    const float* __restrict__ target,
    const float* __restrict__ kern,
    float* __restrict__ partial)
{
    __shared__ float4 hbuf[2][ROWW];   // double-buffered v-conv row, 16.9 KB
    __shared__ float red[4];

    const int tid   = threadIdx.x;
    const int strip = blockIdx.x;      // 0..15
    const int plane = blockIdx.y;      // 0..95
    const int y0    = strip * TH;
    const int c0    = tid * 2;

    // exact 1D factors from the provided 2D kernel
    float w[KS];
    {
        const float inv_a5 = 1.0f / sqrtf(kern[5*KS + 5]);
        #pragma unroll
        for (int j = 0; j < KS; ++j) w[j] = kern[5*KS + j] * inv_a5;
    }

    const float* pP = pred   + (size_t)plane * IMG;
    const float* tP = target + (size_t)plane * IMG;

    // zero guard columns (cols -8..-1 and 512..519), both buffers
    if (tid < GUARD) {
        const float4 z = make_float4(0,0,0,0);
        hbuf[0][tid] = z;                 hbuf[1][tid] = z;
        hbuf[0][GUARD + HWDIM + tid] = z; hbuf[1][GUARD + HWDIM + tid] = z;
    }

    // warm the ring: rows y0-5 .. y0+4 -> slots 0..9; prefetch y0+5
    float ru0[11], rv0[11], ru1[11], rv1[11];
    #pragma unroll
    for (int s = 0; s < 10; ++s)
        loaduv(pP, tP, y0 - 5 + s, c0, ru0[s], rv0[s], ru1[s], rv1[s]);
    float nu0, nv0, nu1, nv1;
    loaduv(pP, tP, y0 + 5, c0, nu0, nv0, nu1, nv1);

    float lsum = 0.f;
    // phase-unrolled by 11 so ring indices are static; 32 = 11 + 11 + 10
#define RS(J) lsum += row_step<(J) % 11>(y0 + base + (J), (base + (J)) & 1, c0, \
                        pP, tP, w, ru0, rv0, ru1, rv1, nu0, nv0, nu1, nv1, hbuf)
    for (int base = 0; base < TH; base += 11) {
        RS(0); RS(1); RS(2); RS(3); RS(4);
        RS(5); RS(6); RS(7); RS(8); RS(9);
        if (base + 10 < TH) { RS(10); }
    }
#undef RS

    // block reduction (deterministic)
    #pragma unroll
    for (int off = 32; off > 0; off >>= 1)
        lsum += __shfl_down(lsum, off, 64);
    if ((tid & 63) == 0) red[tid >> 6] = lsum;
    __syncthreads();
    if (tid == 0)
        partial[plane * STRIPS + strip] = red[0] + red[1] + red[2] + red[3];
}

__global__ __launch_bounds__(64) void ssim_reduce_kernel(
    const float* __restrict__ partial,
    float* __restrict__ out)
{
    const int b    = blockIdx.x;    // image 0..31
    const int lane = threadIdx.x;   // 0..63
    // image b owns partials [48b, 48b+48): planes 3b..3b+2, 16 strips each
    float s = (lane < 48) ? partial[b * 48 + lane] : 0.f;
    #pragma unroll
    for (int off = 32; off > 0; off >>= 1)
        s += __shfl_down(s, off, 64);
    if (lane == 0) out[b] = s * (1.0f / (3.0f * 512.0f * 512.0f));
}

extern "C" void kernel_launch(void* const* d_in, const int* in_sizes, int n_in,
                              void* d_out, int out_size, void* d_ws, size_t ws_size,
                              hipStream_t stream) {
    (void)in_sizes; (void)n_in; (void)out_size; (void)ws_size;
    const float* pred   = (const float*)d_in[0];
    const float* target = (const float*)d_in[1];
    const float* kern   = (const float*)d_in[2];
    float* out     = (float*)d_out;
    float* partial = (float*)d_ws;   // NPARTIAL * 4 = 6144 bytes

    dim3 grid(STRIPS, PLANES);
    ssim_stream_kernel<<<grid, 256, 0, stream>>>(pred, target, kern, partial);
    ssim_reduce_kernel<<<32, 64, 0, stream>>>(partial, out);
}

// Round 4
// 880.330 us; speedup vs baseline: 1.3612x; 1.3612x over previous
//
#include <hip/hip_runtime.h>

#define KS     11
#define HWDIM  512
#define IMG    (HWDIM*HWDIM)
#define TH     32
#define STRIPS 16              // 512 / TH
#define PLANES 96              // 32 images * 3 channels
#define EG     4               // guard entries (even/odd arrays) each side
#define EOW    264             // EG + 256 + EG
#define NPARTIAL (PLANES*STRIPS)   // 1536

__device__ __forceinline__ float ssim_px(float mu_u, float mu_v, float Su, float Sv)
{
    const float C1v = 1e-4f, C2v = 9e-4f, EPSV = 1e-8f;
    const float uu = mu_u*mu_u, vv = mu_v*mu_v;
    const float mu2d = 0.5f*(uu - vv);   // 2 mux muy
    const float mu2s = 0.5f*(uu + vv);   // mux^2 + muy^2
    const float Sd   = 0.5f*(Su - Sv);   // 2 conv(p t)
    const float Ss   = 0.5f*(Su + Sv);   // conv(p^2)+conv(t^2)
    const float A  = mu2d + C1v;
    const float B  = Sd - mu2d + C2v;
    const float Cc = mu2s + C1v;
    const float D  = Ss - mu2s + C2v;
    return A*B / (Cc*D + EPSV);
}

// load one input row (cols 2t,2t+1) and map to u=p'+t', v=p'-t' (zero outside)
#define LOADUV(Y, UA, VA, UB, VB) do {                                        \
    if ((unsigned)(Y) < HWDIM) {                                              \
        const float2 p2 = *(const float2*)(pP + (size_t)(Y)*HWDIM + c0);      \
        const float2 t2 = *(const float2*)(tP + (size_t)(Y)*HWDIM + c0);      \
        UA = 0.5f*(p2.x + t2.x) + 1.0f; VA = 0.5f*(p2.x - t2.x);              \
        UB = 0.5f*(p2.y + t2.y) + 1.0f; VB = 0.5f*(p2.y - t2.y);              \
    } else { UA = 0.f; VA = 0.f; UB = 0.f; VB = 0.f; }                        \
} while(0)

// one vertical tap from ring slot S with weight W, both columns, 4 fields
#define VTAP(W, S) do {                                                       \
    const float tA = (W) * uA##S; muA += tA; SuA = fmaf(tA, uA##S, SuA);      \
    const float sA = (W) * vA##S; mvA += sA; SvA = fmaf(sA, vA##S, SvA);      \
    const float tB = (W) * uB##S; muB += tB; SuB = fmaf(tB, uB##S, SuB);      \
    const float sB = (W) * vB##S; mvB += sB; SvB = fmaf(sB, vB##S, SvB);      \
} while(0)

#define HF(ACC, W, T) do {                                                    \
    ACC.x = fmaf((W), (T).x, ACC.x); ACC.y = fmaf((W), (T).y, ACC.y);         \
    ACC.z = fmaf((W), (T).z, ACC.z); ACC.w = fmaf((W), (T).w, ACC.w);         \
} while(0)

// One output row. S0..S10 are ring-slot suffixes in tap order (phase-rotated):
// insert prefetched row into S10, prefetch YNEXT, vertical conv, LDS exchange
// (even/odd split -> all lanes consecutive, conflict-free), horizontal conv.
#define ROW_STEP(ROWPAR, YNEXT, S0,S1,S2,S3,S4,S5,S6,S7,S8,S9,S10) do {       \
    uA##S10 = nuA; vA##S10 = nvA; uB##S10 = nuB; vB##S10 = nvB;               \
    LOADUV((YNEXT), nuA, nvA, nuB, nvB);                                      \
    float muA=0.f,mvA=0.f,SuA=0.f,SvA=0.f,muB=0.f,mvB=0.f,SuB=0.f,SvB=0.f;    \
    VTAP(w0,S0);  VTAP(w1,S1);  VTAP(w2,S2);  VTAP(w3,S3);  VTAP(w4,S4);      \
    VTAP(w5,S5);  VTAP(w6,S6);  VTAP(w7,S7);  VTAP(w8,S8);  VTAP(w9,S9);      \
    VTAP(w10,S10);                                                            \
    float4* bE = &hbufE[(ROWPAR)][0];                                         \
    float4* bO = &hbufO[(ROWPAR)][0];                                         \
    bE[EG + tid] = make_float4(muA, mvA, SuA, SvA);                           \
    bO[EG + tid] = make_float4(muB, mvB, SuB, SvB);                           \
    __syncthreads();                                                          \
    float4 accA = make_float4(0,0,0,0), accB = make_float4(0,0,0,0);          \
    {                                                                         \
        float4 e, o;                                                          \
        o = bO[EG + tid - 3]; HF(accA, w0,  o);                               \
        e = bE[EG + tid - 2]; HF(accA, w1,  e); HF(accB, w0,  e);             \
        o = bO[EG + tid - 2]; HF(accA, w2,  o); HF(accB, w1,  o);             \
        e = bE[EG + tid - 1]; HF(accA, w3,  e); HF(accB, w2,  e);             \
        o = bO[EG + tid - 1]; HF(accA, w4,  o); HF(accB, w3,  o);             \
        e = bE[EG + tid    ]; HF(accA, w5,  e); HF(accB, w4,  e);             \
        o = bO[EG + tid    ]; HF(accA, w6,  o); HF(accB, w5,  o);             \
        e = bE[EG + tid + 1]; HF(accA, w7,  e); HF(accB, w6,  e);             \
        o = bO[EG + tid + 1]; HF(accA, w8,  o); HF(accB, w7,  o);             \
        e = bE[EG + tid + 2]; HF(accA, w9,  e); HF(accB, w8,  e);             \
        o = bO[EG + tid + 2]; HF(accA, w10, o); HF(accB, w9,  o);             \
        e = bE[EG + tid + 3];                   HF(accB, w10, e);             \
    }                                                                         \
    lsum += ssim_px(accA.x, accA.y, accA.z, accA.w);                          \
    lsum += ssim_px(accB.x, accB.y, accB.z, accB.w);                          \
} while(0)

__global__ __launch_bounds__(256, 3) void ssim_stream_kernel(
    const float* __restrict__ pred,
    const float* __restrict__ target,
    const float* __restrict__ kern,
    float* __restrict__ partial)
{
    __shared__ float4 hbufE[2][EOW];   // even cols: c=2i -> [i]
    __shared__ float4 hbufO[2][EOW];   // odd  cols: c=2i+1 -> [i]
    __shared__ float red[4];

    const int tid   = threadIdx.x;
    const int strip = blockIdx.x;      // 0..15
    const int plane = blockIdx.y;      // 0..95
    const int y0    = strip * TH;
    const int c0    = tid * 2;

    // exact 1D factors from the provided 2D kernel: a_j = k2d[5][j]/sqrt(k2d[5][5])
    const float inv_a5 = 1.0f / sqrtf(kern[5*KS + 5]);
    const float w0  = kern[55+0]*inv_a5,  w1 = kern[55+1]*inv_a5;
    const float w2  = kern[55+2]*inv_a5,  w3 = kern[55+3]*inv_a5;
    const float w4  = kern[55+4]*inv_a5,  w5 = kern[55+5]*inv_a5;
    const float w6  = kern[55+6]*inv_a5,  w7 = kern[55+7]*inv_a5;
    const float w8  = kern[55+8]*inv_a5,  w9 = kern[55+9]*inv_a5;
    const float w10 = kern[55+10]*inv_a5;

    const float* pP = pred   + (size_t)plane * IMG;
    const float* tP = target + (size_t)plane * IMG;

    // zero the guard entries of both buffers (cols <0 and >=512 -> zero taps)
    if (tid < EG) {
        const float4 z = make_float4(0,0,0,0);
        hbufE[0][tid] = z; hbufE[1][tid] = z;
        hbufO[0][tid] = z; hbufO[1][tid] = z;
        hbufE[0][EG+256+tid] = z; hbufE[1][EG+256+tid] = z;
        hbufO[0][EG+256+tid] = z; hbufO[1][EG+256+tid] = z;
    }

    // register ring: 11 slots x {u,v} x {colA,colB} — all NAMED scalars
    float uA0,uA1,uA2,uA3,uA4,uA5,uA6,uA7,uA8,uA9,uA10;
    float vA0,vA1,vA2,vA3,vA4,vA5,vA6,vA7,vA8,vA9,vA10;
    float uB0,uB1,uB2,uB3,uB4,uB5,uB6,uB7,uB8,uB9,uB10;
    float vB0,vB1,vB2,vB3,vB4,vB5,vB6,vB7,vB8,vB9,vB10;
    float nuA, nvA, nuB, nvB;

    // warm the ring: rows y0-5 .. y0+4 into slots 0..9; prefetch y0+5
    LOADUV(y0-5, uA0, vA0, uB0, vB0);
    LOADUV(y0-4, uA1, vA1, uB1, vB1);
    LOADUV(y0-3, uA2, vA2, uB2, vB2);
    LOADUV(y0-2, uA3, vA3, uB3, vB3);
    LOADUV(y0-1, uA4, vA4, uB4, vB4);
    LOADUV(y0+0, uA5, vA5, uB5, vB5);
    LOADUV(y0+1, uA6, vA6, uB6, vB6);
    LOADUV(y0+2, uA7, vA7, uB7, vB7);
    LOADUV(y0+3, uA8, vA8, uB8, vB8);
    LOADUV(y0+4, uA9, vA9, uB9, vB9);
    uA10=0.f; vA10=0.f; uB10=0.f; vB10=0.f;   // filled by first ROW_STEP
    LOADUV(y0+5, nuA, nvA, nuB, nvB);

    float lsum = 0.f;
    // 32 rows = 11 + 11 + 10; phase J -> ring suffixes rotated by J
    for (int base = 0; base < TH; base += 11) {
        const int yb = y0 + base;
        ROW_STEP(((base+0)&1),  yb+0+6,  0,1,2,3,4,5,6,7,8,9,10);
        ROW_STEP(((base+1)&1),  yb+1+6,  1,2,3,4,5,6,7,8,9,10,0);
        ROW_STEP(((base+2)&1),  yb+2+6,  2,3,4,5,6,7,8,9,10,0,1);
        ROW_STEP(((base+3)&1),  yb+3+6,  3,4,5,6,7,8,9,10,0,1,2);
        ROW_STEP(((base+4)&1),  yb+4+6,  4,5,6,7,8,9,10,0,1,2,3);
        ROW_STEP(((base+5)&1),  yb+5+6,  5,6,7,8,9,10,0,1,2,3,4);
        ROW_STEP(((base+6)&1),  yb+6+6,  6,7,8,9,10,0,1,2,3,4,5);
        ROW_STEP(((base+7)&1),  yb+7+6,  7,8,9,10,0,1,2,3,4,5,6);
        ROW_STEP(((base+8)&1),  yb+8+6,  8,9,10,0,1,2,3,4,5,6,7);
        ROW_STEP(((base+9)&1),  yb+9+6,  9,10,0,1,2,3,4,5,6,7,8);
        if (base + 10 < TH) {
            ROW_STEP(((base+10)&1), yb+10+6, 10,0,1,2,3,4,5,6,7,8,9);
        }
    }

    // deterministic block reduction
    #pragma unroll
    for (int off = 32; off > 0; off >>= 1)
        lsum += __shfl_down(lsum, off, 64);
    if ((tid & 63) == 0) red[tid >> 6] = lsum;
    __syncthreads();
    if (tid == 0)
        partial[plane * STRIPS + strip] = red[0] + red[1] + red[2] + red[3];
}

__global__ __launch_bounds__(64) void ssim_reduce_kernel(
    const float* __restrict__ partial,
    float* __restrict__ out)
{
    const int b    = blockIdx.x;    // image 0..31
    const int lane = threadIdx.x;   // 0..63
    // image b owns partials [48b, 48b+48): planes 3b..3b+2, 16 strips each
    float s = (lane < 48) ? partial[b * 48 + lane] : 0.f;
    #pragma unroll
    for (int off = 32; off > 0; off >>= 1)
        s += __shfl_down(s, off, 64);
    if (lane == 0) out[b] = s * (1.0f / (3.0f * 512.0f * 512.0f));
}

extern "C" void kernel_launch(void* const* d_in, const int* in_sizes, int n_in,
                              void* d_out, int out_size, void* d_ws, size_t ws_size,
                              hipStream_t stream) {
    (void)in_sizes; (void)n_in; (void)out_size; (void)ws_size;
    const float* pred   = (const float*)d_in[0];
    const float* target = (const float*)d_in[1];
    const float* kern   = (const float*)d_in[2];
    float* out     = (float*)d_out;
    float* partial = (float*)d_ws;   // NPARTIAL * 4 = 6144 bytes

    dim3 grid(STRIPS, PLANES);
    ssim_stream_kernel<<<grid, 256, 0, stream>>>(pred, target, kern, partial);
    ssim_reduce_kernel<<<32, 64, 0, stream>>>(partial, out);
}

// Round 5
// 108.387 us; speedup vs baseline: 11.0561x; 8.1221x over previous
//
#include <hip/hip_runtime.h>

#define KS     11
#define HWDIM  512
#define IMG    (HWDIM*HWDIM)
#define TH     64
#define STRIPS 8               // 512 / TH
#define PLANES 96              // 32 images * 3 channels
#define GUARD  8
#define HBW    (GUARD + HWDIM + GUARD)   // 528 float4 entries
#define NPARTIAL (PLANES*STRIPS)         // 768

__device__ __forceinline__ float ssim_px(float mu_u, float mu_v, float Su, float Sv)
{
    const float C1v = 1e-4f, C2v = 9e-4f, EPSV = 1e-8f;
    const float uu = mu_u*mu_u, vv = mu_v*mu_v;
    const float mu2d = 0.5f*(uu - vv);   // 2 mux muy
    const float mu2s = 0.5f*(uu + vv);   // mux^2 + muy^2
    const float Sd   = 0.5f*(Su - Sv);   // 2 conv(p't')
    const float Ss   = 0.5f*(Su + Sv);   // conv(p'^2)+conv(t'^2)
    const float A  = mu2d + C1v;
    const float B  = Sd - mu2d + C2v;
    const float Cc = mu2s + C1v;
    const float D  = Ss - mu2s + C2v;
    return A*B / (Cc*D + EPSV);
}

// load one input element (row Y, col tid) and map: u=p'+t', v=p'-t'
// (zero outside the image: conv zero-pads the MAPPED values)
#define LOADUV(Y, U, V) do {                                   \
    if ((unsigned)(Y) < HWDIM) {                               \
        const float p_ = pC[(size_t)(Y) * HWDIM];              \
        const float t_ = tC[(size_t)(Y) * HWDIM];              \
        U = 0.5f*(p_ + t_) + 1.0f;                             \
        V = 0.5f*(p_ - t_);                                    \
    } else { U = 0.f; V = 0.f; }                               \
} while(0)

// one vertical tap: field u and v, mean + second moment
#define VTAP(W, U, V) do {                                     \
    const float tu_ = (W) * (U); mu += tu_; Su = fmaf(tu_, (U), Su); \
    const float tv_ = (W) * (V); mv += tv_; Sv = fmaf(tv_, (V), Sv); \
} while(0)

#define HTAP(W, K) do {                                        \
    const float4 tp_ = hb[GUARD + tid - 5 + (K)];              \
    ax = fmaf((W), tp_.x, ax); ay = fmaf((W), tp_.y, ay);      \
    az = fmaf((W), tp_.z, az); aw = fmaf((W), tp_.w, aw);      \
} while(0)

__global__ __launch_bounds__(512) void ssim_stream_kernel(
    const float* __restrict__ pred,
    const float* __restrict__ target,
    const float* __restrict__ kern,
    float* __restrict__ partial)
{
    __shared__ float4 hbuf[2][HBW];   // 16.9 KB, double-buffered v-conv row
    __shared__ float red[8];

    const int tid   = threadIdx.x;     // 0..511 == column
    const int strip = blockIdx.x;      // 0..7
    const int plane = blockIdx.y;      // 0..95
    const int y0    = strip * TH;

    // exact 1D factors from the provided 2D kernel: a_j = k2d[5][j]/sqrt(k2d[5][5])
    const float inv_a5 = 1.0f / sqrtf(kern[60]);   // kern[5*11+5]
    const float w0  = kern[55]*inv_a5,   w1 = kern[56]*inv_a5;
    const float w2  = kern[57]*inv_a5,   w3 = kern[58]*inv_a5;
    const float w4  = kern[59]*inv_a5,   w5 = kern[60]*inv_a5;
    const float w6  = kern[61]*inv_a5,   w7 = kern[62]*inv_a5;
    const float w8  = kern[63]*inv_a5,   w9 = kern[64]*inv_a5;
    const float w10 = kern[65]*inv_a5;

    const float* pC = pred   + (size_t)plane * IMG + tid;
    const float* tC = target + (size_t)plane * IMG + tid;

    // zero guard entries (cols <0 and >=512), both parities; first loop
    // barrier orders these before any h-pass read, rows never overwrite them
    if (tid < GUARD) {
        const float4 z = make_float4(0,0,0,0);
        hbuf[0][tid] = z;                  hbuf[1][tid] = z;
        hbuf[0][GUARD + HWDIM + tid] = z;  hbuf[1][GUARD + HWDIM + tid] = z;
    }

    // vertical ring: at row r, slots 0..10 hold rows y0+r-5 .. y0+r+5.
    // Entering iteration r: slots 1..10 hold rows r-5..r+4, nu/nv hold r+5.
    float u0,u1,u2,u3,u4,u5,u6,u7,u8,u9,u10;
    float v0,v1,v2,v3,v4,v5,v6,v7,v8,v9,v10;
    float nu, nv;
    u0 = 0.f; v0 = 0.f;
    LOADUV(y0-5, u1, v1);  LOADUV(y0-4, u2, v2);
    LOADUV(y0-3, u3, v3);  LOADUV(y0-2, u4, v4);
    LOADUV(y0-1, u5, v5);  LOADUV(y0+0, u6, v6);
    LOADUV(y0+1, u7, v7);  LOADUV(y0+2, u8, v8);
    LOADUV(y0+3, u9, v9);  LOADUV(y0+4, u10, v10);
    LOADUV(y0+5, nu, nv);

    float lsum = 0.f;
    for (int r = 0; r < TH; ++r) {
        // shift ring down one row
        u0=u1; v0=v1; u1=u2; v1=v2; u2=u3; v2=v3; u3=u4; v3=v4; u4=u5; v4=v5;
        u5=u6; v5=v6; u6=u7; v6=v7; u7=u8; v7=v8; u8=u9; v8=v9; u9=u10; v9=v10;
        u10=nu; v10=nv;
        // prefetch next input row (consumed next iteration)
        LOADUV(y0 + r + 6, nu, nv);

        // vertical 11-tap conv: mu=conv(u), Su=conv(u^2), same for v
        float mu=0.f, mv=0.f, Su=0.f, Sv=0.f;
        VTAP(w0,  u0,  v0);  VTAP(w1,  u1,  v1);  VTAP(w2,  u2,  v2);
        VTAP(w3,  u3,  v3);  VTAP(w4,  u4,  v4);  VTAP(w5,  u5,  v5);
        VTAP(w6,  u6,  v6);  VTAP(w7,  u7,  v7);  VTAP(w8,  u8,  v8);
        VTAP(w9,  u9,  v9);  VTAP(w10, u10, v10);

        float4* hb = &hbuf[r & 1][0];
        hb[GUARD + tid] = make_float4(mu, mv, Su, Sv);
        __syncthreads();

        // horizontal 11-tap conv, consecutive-lane b128 reads (conflict-free)
        float ax=0.f, ay=0.f, az=0.f, aw=0.f;
        HTAP(w0, 0);  HTAP(w1, 1);  HTAP(w2, 2);  HTAP(w3, 3);
        HTAP(w4, 4);  HTAP(w5, 5);  HTAP(w6, 6);  HTAP(w7, 7);
        HTAP(w8, 8);  HTAP(w9, 9);  HTAP(w10, 10);

        lsum += ssim_px(ax, ay, az, aw);
        // no second barrier needed: next row writes the other parity; a wave
        // can only reach parity reuse (r+2) after all waves passed r+1's
        // barrier, which postdates their r reads.
    }

    // deterministic block reduction (8 waves)
    #pragma unroll
    for (int off = 32; off > 0; off >>= 1)
        lsum += __shfl_down(lsum, off, 64);
    if ((tid & 63) == 0) red[tid >> 6] = lsum;
    __syncthreads();
    if (tid == 0) {
        float bsum = 0.f;
        #pragma unroll
        for (int wv = 0; wv < 8; ++wv) bsum += red[wv];
        partial[plane * STRIPS + strip] = bsum;
    }
}

__global__ __launch_bounds__(64) void ssim_reduce_kernel(
    const float* __restrict__ partial,
    float* __restrict__ out)
{
    const int b    = blockIdx.x;    // image 0..31
    const int lane = threadIdx.x;   // 0..63
    // image b owns partials [24b, 24b+24): planes 3b..3b+2, 8 strips each
    float s = (lane < 24) ? partial[b * 24 + lane] : 0.f;
    #pragma unroll
    for (int off = 32; off > 0; off >>= 1)
        s += __shfl_down(s, off, 64);
    if (lane == 0) out[b] = s * (1.0f / (3.0f * 512.0f * 512.0f));
}

extern "C" void kernel_launch(void* const* d_in, const int* in_sizes, int n_in,
                              void* d_out, int out_size, void* d_ws, size_t ws_size,
                              hipStream_t stream) {
    (void)in_sizes; (void)n_in; (void)out_size; (void)ws_size;
    const float* pred   = (const float*)d_in[0];
    const float* target = (const float*)d_in[1];
    const float* kern   = (const float*)d_in[2];
    float* out     = (float*)d_out;
    float* partial = (float*)d_ws;   // NPARTIAL * 4 = 3072 bytes

    dim3 grid(STRIPS, PLANES);
    ssim_stream_kernel<<<grid, 512, 0, stream>>>(pred, target, kern, partial);
    ssim_reduce_kernel<<<32, 64, 0, stream>>>(partial, out);
}